// Round 3
// baseline (384.034 us; speedup 1.0000x reference)
//
#include <hip/hip_runtime.h>
#include <hip/hip_bf16.h>
#include <cstdint>

#define TOKENS 8192
#define DIN 1024
#define DOUT 1024
#define NE 8

typedef __bf16 bf16;
typedef __attribute__((ext_vector_type(8))) __bf16 bf16x8;
typedef __attribute__((ext_vector_type(4))) float floatx4;
typedef __attribute__((ext_vector_type(2))) float floatx2;

// async global->LDS, 16B per lane. LDS dest must be wave-uniform base + lane*16.
__device__ __forceinline__ void async16(const void* gptr, void* lptr) {
  __builtin_amdgcn_global_load_lds(
      (const __attribute__((address_space(1))) void*)gptr,
      (__attribute__((address_space(3))) void*)lptr,
      16, 0, 0);
}

// ---------------------------------------------------------------------------
// R9: prep split into gate_kernel + trans_kernel (code identical to R7/R8's
// fused prep) so rocprof attributes the ~97us prep cost per-kernel next round.
// ---------------------------------------------------------------------------
__global__ __launch_bounds__(256) void gate_kernel(
    const float* __restrict__ x, const float* __restrict__ gw,
    const float* __restrict__ gb, float* __restrict__ g,
    bf16* __restrict__ xb) {
  __shared__ __align__(16) float smem[NE * DIN];  // 32 KB

  const int tid = threadIdx.x;
#pragma unroll
  for (int k = 0; k < 8; ++k) {
    const int base = (k * 256 + tid) * 4;
    const floatx4 v = *(const floatx4*)(gw + base);
#pragma unroll
    for (int m = 0; m < 4; ++m) {
      const int j = base + m;
      smem[(j & 7) * DIN + (j >> 3)] = v[m];
    }
  }
  __syncthreads();

  const int lane = tid & 63;
  const int wave = tid >> 6;
#pragma unroll
  for (int tt = 0; tt < 4; ++tt) {
    const int t = blockIdx.x * 16 + wave * 4 + tt;
    const float* xr = x + (size_t)t * DIN;
    bf16* xbr = xb + (size_t)t * DIN;

    float acc[NE];
#pragma unroll
    for (int e = 0; e < NE; ++e) acc[e] = 0.f;

#pragma unroll
    for (int it = 0; it < 4; ++it) {
      const int i = it * 256 + lane * 4;
      const floatx4 xv = *(const floatx4*)(xr + i);
      union { bf16 b[4]; uint64_t u; } cv;
#pragma unroll
      for (int m = 0; m < 4; ++m) cv.b[m] = (bf16)xv[m];
      *(uint64_t*)(xbr + i) = cv.u;
#pragma unroll
      for (int e = 0; e < NE; ++e) {
        const floatx4 wv = *(const floatx4*)(smem + e * DIN + i);
        acc[e] += xv[0] * wv[0] + xv[1] * wv[1] + xv[2] * wv[2] + xv[3] * wv[3];
      }
    }
#pragma unroll
    for (int e = 0; e < NE; ++e)
#pragma unroll
      for (int off = 32; off > 0; off >>= 1)
        acc[e] += __shfl_xor(acc[e], off, 64);

    float lg[NE];
    float mx = -3.0e38f;
#pragma unroll
    for (int e = 0; e < NE; ++e) { lg[e] = acc[e] + gb[e]; mx = fmaxf(mx, lg[e]); }
    float s = 0.f;
#pragma unroll
    for (int e = 0; e < NE; ++e) { lg[e] = __expf(lg[e] - mx); s += lg[e]; }
    const float inv = 1.f / s;
    if (lane == 0) {
      floatx4 o0, o1;
#pragma unroll
      for (int e = 0; e < 4; ++e) { o0[e] = lg[e] * inv; o1[e] = lg[e + 4] * inv; }
      *(floatx4*)(g + (size_t)t * NE) = o0;
      *(floatx4*)(g + (size_t)t * NE + 4) = o1;
    }
  }
}

__global__ __launch_bounds__(256) void trans_kernel(
    const float* __restrict__ w, bf16* __restrict__ wt) {
  __shared__ __align__(16) float tile[64][65];
  const int b = blockIdx.x;
  const int e = b >> 8;
  const int i0 = ((b >> 4) & 15) * 64;
  const int o0 = (b & 15) * 64;
  const int tid = threadIdx.x;
  const int c4 = (tid & 15) * 4;
  const int r = tid >> 4;

  const float* src = w + ((size_t)e * DIN + i0) * DOUT + o0;
#pragma unroll
  for (int rr = r; rr < 64; rr += 16) {
    const floatx4 v = *(const floatx4*)(src + (size_t)rr * DOUT + c4);
    tile[rr][c4] = v[0]; tile[rr][c4 + 1] = v[1];
    tile[rr][c4 + 2] = v[2]; tile[rr][c4 + 3] = v[3];
  }
  __syncthreads();
  bf16* dst = wt + ((size_t)e * DOUT + o0) * DIN + i0;
#pragma unroll
  for (int rr = r; rr < 64; rr += 16) {
    union { bf16 b[4]; uint64_t u; } cv;
#pragma unroll
    for (int j = 0; j < 4; ++j) cv.b[j] = (bf16)tile[c4 + j][rr];
    *(uint64_t*)(dst + (size_t)rr * DIN + c4) = cv.u;
  }
}

// ---------------------------------------------------------------------------
// Fused MoE GEMM, R9: A direct-to-register, B-only LDS pipeline.
// R8 cycle model: per-K-tile wall 2532 cyc vs MFMA demand 1242; LDS pipe
// demand (128 ds_read_b128 x 12 + 64KB staging writes) ~2100 cyc => LDS-BW
// bound. A's fragment layout (row=im*16+lr, k=kk*32+lq*8) is one contiguous
// 16B global load per lane — no LDS needed. Removing A from LDS cuts LDS
// demand to ~1050 cyc (< MFMA 1242) => MFMA-bound.
// A-frags prefetched one tile ahead (avn/avc, +64 VGPR, ~245 total, still
// 2 waves/SIMD). B keeps verified dbuf+swizzle+async16; staging issued at
// tile top so the barrier drain waits ~nothing.
// ---------------------------------------------------------------------------
__global__ __launch_bounds__(256, 2) void moe_gemm(
    const bf16* __restrict__ xb, const bf16* __restrict__ wt,
    const float* __restrict__ g, float* __restrict__ out) {
  __shared__ __align__(16) bf16 Bs[2][128 * 64];  // 2 x 16KB

  const int tid = threadIdx.x;
  // XCD swizzle (verified R7): per-XCD chunk = 16 bm x 4 bn.
  const int c = blockIdx.x & 7;
  const int jj = blockIdx.x >> 3;
  const int bm = (c >> 1) * 16 + (jj & 15);   // 0..63
  const int bn = (c & 1) * 4 + (jj >> 4);     // 0..7
  const int lane = tid & 63;
  const int wave = tid >> 6;
  const int wm = wave >> 1, wn = wave & 1;
  const int lr = lane & 15, lq = lane >> 4;

  // B staging: srow in 0..31 (+32 per pass), 8 16B-units per 64-col row.
  const int srow = tid >> 3;
  const int scol = (((tid & 7) ^ (srow & 7)) << 3);
  const int kx = lr & 7;

  const bf16* const bgp = wt + (size_t)(bn * 128 + srow) * DIN + scol;
  // per-lane A base: row = bm*128 + wm*64 + lr, col = lq*8 (+im*16 rows, +kk*32)
  const bf16* const abase = xb + (size_t)(bm * 128 + wm * 64 + lr) * DIN + lq * 8;

  const floatx4 fzero = {0.f, 0.f, 0.f, 0.f};
  floatx4 accF[4][4], accE[4][4];
#pragma unroll
  for (int im = 0; im < 4; ++im)
#pragma unroll
    for (int in = 0; in < 4; ++in) { accF[im][in] = fzero; accE[im][in] = fzero; }

  const int tok0 = bm * 128 + wm * 64;

  // prologue: stage B tile 0, load A-frags tile 0
  {
    bf16* const blp = &Bs[0][tid * 8];
#pragma unroll
    for (int j = 0; j < 4; ++j)
      async16(bgp + (size_t)(32 * j) * DIN, blp + j * 2048);
  }
  bf16x8 avc[2][4], avn[2][4];
#pragma unroll
  for (int kk = 0; kk < 2; ++kk)
#pragma unroll
    for (int im = 0; im < 4; ++im)
      avc[kk][im] = *(const bf16x8*)(abase + (size_t)(im * 16) * DIN + kk * 32);
  __syncthreads();

  // 128 flattened K-tiles: t = e*16 + kt, k0 = kt*64.
  for (int t = 0; t < 128; ++t) {
    const bf16* const Bb = &Bs[t & 1][0];

    // 1) B fragment reads for both kk halves
    bf16x8 bv[2][4];
#pragma unroll
    for (int kk = 0; kk < 2; ++kk) {
      const int kg = ((kk * 4 + lq) ^ kx) << 3;
#pragma unroll
      for (int in = 0; in < 4; ++in)
        bv[kk][in] = *(const bf16x8*)(Bb + (wn * 64 + in * 16 + lr) * 64 + kg);
    }

    const int t1 = t + 1;
    if (t1 < 128) {
      const size_t koff = (size_t)((t1 & 15) << 6);
      // 2) prefetch A-frags for t+1 into registers
#pragma unroll
      for (int kk = 0; kk < 2; ++kk)
#pragma unroll
        for (int im = 0; im < 4; ++im)
          avn[kk][im] = *(const bf16x8*)(abase + (size_t)(im * 16) * DIN +
                                         koff + kk * 32);
      // 3) stage B for t+1 into other buffer
      const bf16* const bsrc = bgp + ((size_t)(t1 >> 4) << 20) + koff;
      bf16* const blp = &Bs[t1 & 1][tid * 8];
#pragma unroll
      for (int j = 0; j < 4; ++j)
        async16(bsrc + (size_t)(32 * j) * DIN, blp + j * 2048);
    }

    // 4) MFMA kk=0
    __builtin_amdgcn_s_setprio(1);
#pragma unroll
    for (int im = 0; im < 4; ++im)
#pragma unroll
      for (int in = 0; in < 4; ++in)
        accE[im][in] = __builtin_amdgcn_mfma_f32_16x16x32_bf16(
            avc[0][im], bv[0][in], accE[im][in], 0, 0, 0);
    __builtin_amdgcn_s_setprio(0);

    // 5) MFMA kk=1
    __builtin_amdgcn_s_setprio(1);
#pragma unroll
    for (int im = 0; im < 4; ++im)
#pragma unroll
      for (int in = 0; in < 4; ++in)
        accE[im][in] = __builtin_amdgcn_mfma_f32_16x16x32_bf16(
            avc[1][im], bv[1][in], accE[im][in], 0, 0, 0);
    __builtin_amdgcn_s_setprio(0);

    // 6) expert boundary: fold accE into accF with gate weights
    if ((t & 15) == 15) {
      const int e = t >> 4;
#pragma unroll
      for (int im = 0; im < 4; ++im) {
        float gv[4];
#pragma unroll
        for (int r = 0; r < 4; ++r)
          gv[r] = g[(size_t)(tok0 + im * 16 + lq * 4 + r) * NE + e];
#pragma unroll
        for (int in = 0; in < 4; ++in)
#pragma unroll
          for (int r = 0; r < 4; ++r) {
            accF[im][in][r] += gv[r] * accE[im][in][r];
            accE[im][in][r] = 0.f;
          }
      }
    }

    // 7) boundary barrier (drains staging + avn loads, both issued at tile top)
    __syncthreads();

    // 8) rotate A-frag registers
#pragma unroll
    for (int kk = 0; kk < 2; ++kk)
#pragma unroll
      for (int im = 0; im < 4; ++im)
        avc[kk][im] = avn[kk][im];
  }

#pragma unroll
  for (int im = 0; im < 4; ++im)
#pragma unroll
    for (int in = 0; in < 4; ++in) {
      const int col = bn * 128 + wn * 64 + in * 16 + lr;
#pragma unroll
      for (int r = 0; r < 4; ++r)
        out[(size_t)(tok0 + im * 16 + lq * 4 + r) * DOUT + col] =
            accF[im][in][r];
    }
}

// ---------------------------------------------------------------------------
extern "C" void kernel_launch(void* const* d_in, const int* in_sizes, int n_in,
                              void* d_out, int out_size, void* d_ws,
                              size_t ws_size, hipStream_t stream) {
  const float* x  = (const float*)d_in[0];
  const float* gw = (const float*)d_in[1];
  const float* gb = (const float*)d_in[2];
  const float* w  = (const float*)d_in[3];
  float* out = (float*)d_out;

  char* ws = (char*)d_ws;
  float* g  = (float*)ws;
  bf16* xb  = (bf16*)(ws + 262144);
  bf16* wt  = (bf16*)(ws + 262144 + (size_t)TOKENS * DIN * 2);

  trans_kernel<<<2048, 256, 0, stream>>>(w, wt);
  gate_kernel<<<512, 256, 0, stream>>>(x, gw, gb, g, xb);
  moe_gemm<<<512, 256, 0, stream>>>(xb, wt, g, out);
}

// Round 5
// 242.086 us; speedup vs baseline: 1.5864x; 1.5864x over previous
//
#include <hip/hip_runtime.h>
#include <hip/hip_bf16.h>
#include <cstdint>

#define TOKENS 8192
#define DIN 1024
#define DOUT 1024
#define NE 8

typedef __bf16 bf16;
typedef __attribute__((ext_vector_type(8))) __bf16 bf16x8;
typedef __attribute__((ext_vector_type(4))) float floatx4;
typedef __attribute__((ext_vector_type(2))) float floatx2;

// async global->LDS, 16B per lane. LDS dest must be wave-uniform base + lane*16.
__device__ __forceinline__ void async16(const void* gptr, void* lptr) {
  __builtin_amdgcn_global_load_lds(
      (const __attribute__((address_space(1))) void*)gptr,
      (__attribute__((address_space(3))) void*)lptr,
      16, 0, 0);
}

// ---------------------------------------------------------------------------
// R11 = R10 resubmitted (container infra failure, no counters returned).
// Gate: computes gate softmax AND writes x as bf16 in FRAGMENT-MAJOR layout
// xbf[tg][kt][kk][lq][tok16][8] (tg = token>>4, kt = k-tile of 64, kk =
// 32-half, lq = 8-col group) so moe_gemm's A-frag loads are lane-contiguous
// 1KB dwordx4 (R9's gather — 16 lines/instr — fixed).
// Two half-passes (8 tokens each) keep LDS = 32KB gw + 16.5KB xtile < 64KB.
// ---------------------------------------------------------------------------
__global__ __launch_bounds__(256) void gate_kernel(
    const float* __restrict__ x, const float* __restrict__ gw,
    const float* __restrict__ gb, float* __restrict__ g,
    bf16* __restrict__ xbf) {
  __shared__ __align__(16) float gws[NE * DIN];   // 32 KB, gw transposed
  __shared__ __align__(16) bf16 xtile[8][1032];   // 16.5 KB (pad 8 elems)

  const int tid = threadIdx.x;
  const int bg = blockIdx.x;
#pragma unroll
  for (int k = 0; k < 8; ++k) {
    const int base = (k * 256 + tid) * 4;
    const floatx4 v = *(const floatx4*)(gw + base);
#pragma unroll
    for (int m = 0; m < 4; ++m) {
      const int j = base + m;
      gws[(j & 7) * DIN + (j >> 3)] = v[m];
    }
  }
  __syncthreads();

  const int lane = tid & 63;
  const int wave = tid >> 6;

#pragma unroll
  for (int h = 0; h < 2; ++h) {
#pragma unroll
    for (int tt = 0; tt < 2; ++tt) {
      const int tl = h * 8 + tt * 4 + wave;   // token-in-group 0..15
      const int t = bg * 16 + tl;
      const float* xr = x + (size_t)t * DIN;
      bf16* const xrow = &xtile[tl & 7][0];

      float acc[NE];
#pragma unroll
      for (int e = 0; e < NE; ++e) acc[e] = 0.f;

#pragma unroll
      for (int it = 0; it < 4; ++it) {
        const int i = it * 256 + lane * 4;
        const floatx4 xv = *(const floatx4*)(xr + i);
        union { bf16 b[4]; uint64_t u; } cv;
#pragma unroll
        for (int m = 0; m < 4; ++m) cv.b[m] = (bf16)xv[m];
        *(uint64_t*)(xrow + i) = cv.u;
#pragma unroll
        for (int e = 0; e < NE; ++e) {
          const floatx4 wv = *(const floatx4*)(gws + e * DIN + i);
          acc[e] += xv[0] * wv[0] + xv[1] * wv[1] + xv[2] * wv[2] + xv[3] * wv[3];
        }
      }
#pragma unroll
      for (int e = 0; e < NE; ++e)
#pragma unroll
        for (int off = 32; off > 0; off >>= 1)
          acc[e] += __shfl_xor(acc[e], off, 64);

      float lg[NE];
      float mx = -3.0e38f;
#pragma unroll
      for (int e = 0; e < NE; ++e) { lg[e] = acc[e] + gb[e]; mx = fmaxf(mx, lg[e]); }
      float s = 0.f;
#pragma unroll
      for (int e = 0; e < NE; ++e) { lg[e] = __expf(lg[e] - mx); s += lg[e]; }
      const float inv = 1.f / s;
      if (lane == 0) {
        floatx4 o0, o1;
#pragma unroll
        for (int e = 0; e < 4; ++e) { o0[e] = lg[e] * inv; o1[e] = lg[e + 4] * inv; }
        *(floatx4*)(g + (size_t)t * NE) = o0;
        *(floatx4*)(g + (size_t)t * NE + 4) = o1;
      }
    }
    __syncthreads();
    // write out half h in fragment-major order: 4 passes x 256 units of 16B
#pragma unroll
    for (int p = 0; p < 4; ++p) {
      const int u = p * 256 + tid;           // [0,1024)
      const int lr3 = u & 7;
      const int lq = (u >> 3) & 3;
      const int kkv = (u >> 5) & 1;
      const int kt = u >> 6;                 // [0,16)
      const bf16x8 v = *(const bf16x8*)(&xtile[lr3][kt * 64 + kkv * 32 + lq * 8]);
      const size_t off = (size_t)bg * 16384 +
          (size_t)((((kt * 2 + kkv) * 4 + lq) * 16) + h * 8 + lr3) * 8;
      *(bf16x8*)(xbf + off) = v;
    }
    __syncthreads();
  }
}

__global__ __launch_bounds__(256) void trans_kernel(
    const float* __restrict__ w, bf16* __restrict__ wt) {
  __shared__ __align__(16) float tile[64][65];
  const int b = blockIdx.x;
  const int e = b >> 8;
  const int i0 = ((b >> 4) & 15) * 64;
  const int o0 = (b & 15) * 64;
  const int tid = threadIdx.x;
  const int c4 = (tid & 15) * 4;
  const int r = tid >> 4;

  const float* src = w + ((size_t)e * DIN + i0) * DOUT + o0;
#pragma unroll
  for (int rr = r; rr < 64; rr += 16) {
    const floatx4 v = *(const floatx4*)(src + (size_t)rr * DOUT + c4);
    tile[rr][c4] = v[0]; tile[rr][c4 + 1] = v[1];
    tile[rr][c4 + 2] = v[2]; tile[rr][c4 + 3] = v[3];
  }
  __syncthreads();
  bf16* dst = wt + ((size_t)e * DOUT + o0) * DIN + i0;
#pragma unroll
  for (int rr = r; rr < 64; rr += 16) {
    union { bf16 b[4]; uint64_t u; } cv;
#pragma unroll
    for (int j = 0; j < 4; ++j) cv.b[j] = (bf16)tile[c4 + j][rr];
    *(uint64_t*)(dst + (size_t)rr * DIN + c4) = cv.u;
  }
}

// ---------------------------------------------------------------------------
// Fused MoE GEMM, R11 (=R10): A direct-to-register from FRAGMENT-MAJOR xbf
// (coalesced 1KB per load instr — fixes R9's 16-lines/instr gather), B-only
// LDS with the R8-verified dbuf+swizzle+async16 single-barrier pipeline.
// Cycle model per CU per K-tile: LDS = 64 ds_read_b128 (768) + 32KB stage
// writes (256) ~= 1024 cyc < MFMA 1242 cyc => MFMA-bound.
// A-frag addr: xbf elem ofs = tg*16384 + (kt*2+kk)*512 + lane*8, tg =
// bm*8+wm*4+im. A re-read per expert from L2 (same bytes R8 staged).
// ---------------------------------------------------------------------------
__global__ __launch_bounds__(256, 2) void moe_gemm(
    const bf16* __restrict__ xbf, const bf16* __restrict__ wt,
    const float* __restrict__ g, float* __restrict__ out) {
  __shared__ __align__(16) bf16 Bs[2][128 * 64];  // 2 x 16KB

  const int tid = threadIdx.x;
  // XCD swizzle (verified R7): per-XCD chunk = 16 bm x 4 bn.
  const int c = blockIdx.x & 7;
  const int jj = blockIdx.x >> 3;
  const int bm = (c >> 1) * 16 + (jj & 15);   // 0..63
  const int bn = (c & 1) * 4 + (jj >> 4);     // 0..7
  const int lane = tid & 63;
  const int wave = tid >> 6;
  const int wm = wave >> 1, wn = wave & 1;
  const int lr = lane & 15, lq = lane >> 4;

  // B staging (verified R8): srow 0..31 (+32/pass), swizzled col.
  const int srow = tid >> 3;
  const int scol = (((tid & 7) ^ (srow & 7)) << 3);
  const int kx = lr & 7;

  const bf16* const bgp = wt + (size_t)(bn * 128 + srow) * DIN + scol;
  const bf16* const abase = xbf + (size_t)(bm * 8 + wm * 4) * 16384 + lane * 8;

  const floatx4 fzero = {0.f, 0.f, 0.f, 0.f};
  floatx4 accF[4][4], accE[4][4];
#pragma unroll
  for (int im = 0; im < 4; ++im)
#pragma unroll
    for (int in = 0; in < 4; ++in) { accF[im][in] = fzero; accE[im][in] = fzero; }

  const int tok0 = bm * 128 + wm * 64;

  // prologue: stage B tile 0, load A-frags tile 0 (kt=0)
  {
    bf16* const blp = &Bs[0][tid * 8];
#pragma unroll
    for (int j = 0; j < 4; ++j)
      async16(bgp + (size_t)(32 * j) * DIN, blp + j * 2048);
  }
  bf16x8 avc[2][4], avn[2][4];
#pragma unroll
  for (int kk = 0; kk < 2; ++kk)
#pragma unroll
    for (int im = 0; im < 4; ++im)
      avc[kk][im] = *(const bf16x8*)(abase + (size_t)im * 16384 + kk * 512);
  __syncthreads();

  // 128 flattened K-tiles: t = e*16 + kt.
  for (int t = 0; t < 128; ++t) {
    const bf16* const Bb = &Bs[t & 1][0];

    // 1) B fragment reads for both kk halves
    bf16x8 bv[2][4];
#pragma unroll
    for (int kk = 0; kk < 2; ++kk) {
      const int kg = ((kk * 4 + lq) ^ kx) << 3;
#pragma unroll
      for (int in = 0; in < 4; ++in)
        bv[kk][in] = *(const bf16x8*)(Bb + (wn * 64 + in * 16 + lr) * 64 + kg);
    }

    const int t1 = t + 1;
    if (t1 < 128) {
      const int kt1 = t1 & 15;
      // 2) prefetch A-frags for t+1 (coalesced 1KB dwordx4 each)
#pragma unroll
      for (int kk = 0; kk < 2; ++kk)
#pragma unroll
        for (int im = 0; im < 4; ++im)
          avn[kk][im] = *(const bf16x8*)(abase + (size_t)im * 16384 +
                                         (kt1 * 2 + kk) * 512);
      // 3) stage B for t+1 into other buffer
      const bf16* const bsrc = bgp + ((size_t)(t1 >> 4) << 20) + (size_t)kt1 * 64;
      bf16* const blp = &Bs[t1 & 1][tid * 8];
#pragma unroll
      for (int j = 0; j < 4; ++j)
        async16(bsrc + (size_t)(32 * j) * DIN, blp + j * 2048);
    }

    // 4) MFMA kk=0
    __builtin_amdgcn_s_setprio(1);
#pragma unroll
    for (int im = 0; im < 4; ++im)
#pragma unroll
      for (int in = 0; in < 4; ++in)
        accE[im][in] = __builtin_amdgcn_mfma_f32_16x16x32_bf16(
            avc[0][im], bv[0][in], accE[im][in], 0, 0, 0);
    __builtin_amdgcn_s_setprio(0);

    // 5) MFMA kk=1
    __builtin_amdgcn_s_setprio(1);
#pragma unroll
    for (int im = 0; im < 4; ++im)
#pragma unroll
      for (int in = 0; in < 4; ++in)
        accE[im][in] = __builtin_amdgcn_mfma_f32_16x16x32_bf16(
            avc[1][im], bv[1][in], accE[im][in], 0, 0, 0);
    __builtin_amdgcn_s_setprio(0);

    // 6) expert boundary: fold accE into accF with gate weights
    if ((t & 15) == 15) {
      const int e = t >> 4;
#pragma unroll
      for (int im = 0; im < 4; ++im) {
        float gv[4];
#pragma unroll
        for (int r = 0; r < 4; ++r)
          gv[r] = g[(size_t)(tok0 + im * 16 + lq * 4 + r) * NE + e];
#pragma unroll
        for (int in = 0; in < 4; ++in)
#pragma unroll
          for (int r = 0; r < 4; ++r) {
            accF[im][in][r] += gv[r] * accE[im][in][r];
            accE[im][in][r] = 0.f;
          }
      }
    }

    // 7) boundary barrier (drains B staging + avn loads, issued at tile top)
    __syncthreads();

    // 8) rotate A-frag registers
#pragma unroll
    for (int kk = 0; kk < 2; ++kk)
#pragma unroll
      for (int im = 0; im < 4; ++im)
        avc[kk][im] = avn[kk][im];
  }

#pragma unroll
  for (int im = 0; im < 4; ++im)
#pragma unroll
    for (int in = 0; in < 4; ++in) {
      const int col = bn * 128 + wn * 64 + in * 16 + lr;
#pragma unroll
      for (int r = 0; r < 4; ++r)
        out[(size_t)(tok0 + im * 16 + lq * 4 + r) * DOUT + col] =
            accF[im][in][r];
    }
}

// ---------------------------------------------------------------------------
extern "C" void kernel_launch(void* const* d_in, const int* in_sizes, int n_in,
                              void* d_out, int out_size, void* d_ws,
                              size_t ws_size, hipStream_t stream) {
  const float* x  = (const float*)d_in[0];
  const float* gw = (const float*)d_in[1];
  const float* gb = (const float*)d_in[2];
  const float* w  = (const float*)d_in[3];
  float* out = (float*)d_out;

  char* ws = (char*)d_ws;
  float* g   = (float*)ws;
  bf16* xbf  = (bf16*)(ws + 262144);
  bf16* wt   = (bf16*)(ws + 262144 + (size_t)TOKENS * DIN * 2);

  trans_kernel<<<2048, 256, 0, stream>>>(w, wt);
  gate_kernel<<<512, 256, 0, stream>>>(x, gw, gb, g, xbf);
  moe_gemm<<<512, 256, 0, stream>>>(xbf, wt, g, out);
}